// Round 3
// baseline (14727.142 us; speedup 1.0000x reference)
//
#include <hip/hip_runtime.h>
#include <stdint.h>
#include <math.h>

#define KNB 40
static constexpr int NB = 16;   // batch

// ---------------- workspace layout (bytes), total ~164 MB ----------------
static constexpr size_t OFF_W4  = 0;                        // 4 * 5,898,240 bf16 = 47,185,920 B
static constexpr size_t OFF_Hb  = 47185920;                 // 47,185,920 bf16 = 94,371,840 B
static constexpr size_t OFF_FA  = 141557760;                // 2,359,296 f32
static constexpr size_t OFF_FB  = 150994944;                // 2,359,296 f32
static constexpr size_t OFF_XA  = 160432128;                // 16*1024*3 f32
static constexpr size_t OFF_XB  = 160628736;
static constexpr size_t OFF_FPS = 160825344;                // 16*1024 int
static constexpr size_t OFF_KNN = 160890880;                // 16*1024*40 int
static constexpr size_t OFF_SUM = 163512320;                // 1152 f32
static constexpr size_t OFF_SQ  = 163516928;                // 1152 f32
static constexpr size_t OFF_SC1 = 163521536;                // 1152 f32
static constexpr size_t OFF_SH1 = 163526144;
static constexpr size_t OFF_SC2 = 163530752;
static constexpr size_t OFF_SH2 = 163535360;
static constexpr size_t OFF_DST = 163539968;                // 2 doubles
static constexpr size_t OFF_INV = 163539984;                // 1 f32

// ---------------- bf16 helpers (manual, RNE) ----------------
__device__ static inline uint16_t f2bf(float f){
  uint32_t u = __float_as_uint(f);
  uint32_t r = u + 0x7fffu + ((u >> 16) & 1u);
  return (uint16_t)(r >> 16);
}

// ---------------- JAX Threefry-2x32 (exact) ----------------
__host__ __device__ static inline uint32_t rotl32(uint32_t v, int d){ return (v<<d)|(v>>(32-d)); }
#define TF_RND(r) { x0 += x1; x1 = rotl32(x1,(r)); x1 ^= x0; }
__host__ __device__ static inline void tf2x32(uint32_t k0, uint32_t k1, uint32_t& x0, uint32_t& x1){
  uint32_t ks2 = k0 ^ k1 ^ 0x1BD11BDAu;
  x0 += k0; x1 += k1;
  TF_RND(13) TF_RND(15) TF_RND(26) TF_RND(6)   x0 += k1;  x1 += ks2 + 1u;
  TF_RND(17) TF_RND(29) TF_RND(16) TF_RND(24)  x0 += ks2; x1 += k0 + 2u;
  TF_RND(13) TF_RND(15) TF_RND(26) TF_RND(6)   x0 += k0;  x1 += k1 + 3u;
  TF_RND(17) TF_RND(29) TF_RND(16) TF_RND(24)  x0 += k1;  x1 += ks2 + 4u;
  TF_RND(13) TF_RND(15) TF_RND(26) TF_RND(6)   x0 += ks2; x1 += k0 + 5u;
}

__device__ static inline float freq_of(int t, int f){
  return exp2f(-((float)t / (float)f) * 9.965784284662087f);  // 1000^(-t/f)
}

// ---------------- embed ----------------
__global__ __launch_bounds__(256) void k_embed(const float* __restrict__ x,
                                               const float* __restrict__ w,
                                               float* __restrict__ out){
  __shared__ float sw[216];
  int t = threadIdx.x;
  if (t < 216) sw[t] = w[t];
  __syncthreads();
  int gid = blockIdx.x*256 + t;
  int n = gid & 2047, b = gid >> 11;
  float x0 = x[((size_t)b*3+0)*2048 + n];
  float x1 = x[((size_t)b*3+1)*2048 + n];
  float x2 = x[((size_t)b*3+2)*2048 + n];
  #pragma unroll 4
  for (int o = 0; o < 72; ++o){
    float v = sw[o*3]*x0 + sw[o*3+1]*x1 + sw[o*3+2]*x2;
    out[((size_t)b*72 + o)*2048 + n] = v;
  }
}

__global__ __launch_bounds__(256) void k_chan_stats_f32(const float* __restrict__ in, int C, int M,
                                                        float* __restrict__ SUMf, float* __restrict__ SQf){
  int c = blockIdx.x, b = blockIdx.y;
  const float* p = in + ((size_t)b*C + c)*M;
  float s = 0.f, s2 = 0.f;
  for (int m = threadIdx.x; m < M; m += 256){ float v = p[m]; s += v; s2 += v*v; }
  __shared__ float sa[256], sb[256];
  int t = threadIdx.x;
  sa[t] = s; sb[t] = s2; __syncthreads();
  for (int o = 128; o > 0; o >>= 1){
    if (t < o){ sa[t] += sa[t+o]; sb[t] += sb[t+o]; }
    __syncthreads();
  }
  if (t == 0){ atomicAdd(&SUMf[c], sa[0]); atomicAdd(&SQf[c], sb[0]); }
}

__global__ void k_bn_finalize_f32(const float* __restrict__ SUMf, const float* __restrict__ SQf,
                                  int C, double Mn, const float* __restrict__ gamma,
                                  const float* __restrict__ beta, float* __restrict__ scale,
                                  float* __restrict__ shift){
  int c = blockIdx.x*blockDim.x + threadIdx.x;
  if (c >= C) return;
  double mean = (double)SUMf[c] / Mn;
  double var = (double)SQf[c] / Mn - mean*mean;
  if (var < 0.0) var = 0.0;
  float sc = gamma[c] / sqrtf((float)var + 1e-5f);
  scale[c] = sc;
  shift[c] = beta[c] - (float)mean * sc;
}

__global__ __launch_bounds__(256) void k_bn_apply(float* __restrict__ buf,
                                                  const float* __restrict__ scale,
                                                  const float* __restrict__ shift,
                                                  int C, int M, long long total){
  long long idx = (long long)blockIdx.x*256 + threadIdx.x;
  if (idx >= total) return;
  int c = (int)((idx / M) % C);
  float v = buf[idx]*scale[c] + shift[c];
  buf[idx] = fmaxf(v, 0.f);
}

// ---------------- sampling / knn ----------------
// JAX partitionable threefry: bits[m] = x0^x1 of cipher(k2, counter=(0, m));
// k2 = second foldlike-split subkey = full cipher output of (0, 1) under base key.
__global__ __launch_bounds__(256) void k_fps(const float* __restrict__ xyz, float* __restrict__ lc,
                                             int* __restrict__ fps, int ncur, int g,
                                             uint32_t ka, uint32_t kb){
  int m = blockIdx.x*256 + threadIdx.x;
  int total = NB * g;
  if (m >= total) return;
  uint32_t x0 = 0u, x1 = (uint32_t)m;
  tf2x32(ka, kb, x0, x1);
  uint32_t v = x0 ^ x1;
  int idx = (int)(v & (uint32_t)(ncur - 1));
  fps[m] = idx;
  int b = m / g;
  const float* s = xyz + ((size_t)b*ncur + idx)*3;
  float* d = lc + (size_t)m*3;
  d[0] = s[0]; d[1] = s[1]; d[2] = s[2];
}

template<int CNT>
__global__ __launch_bounds__(64) void k_knn(const float* __restrict__ xyz,
                                            const float* __restrict__ lc,
                                            int* __restrict__ knn, int ncur, int g){
  int row = blockIdx.x;                 // b*g + j
  int b = row / g;
  int lane = threadIdx.x;
  float lx = lc[row*3+0], ly = lc[row*3+1], lz = lc[row*3+2];
  float ln = lx*lx + ly*ly + lz*lz;
  const float* xb = xyz + (size_t)b*ncur*3;
  unsigned long long pk[CNT];
  #pragma unroll
  for (int t = 0; t < CNT; ++t){
    int n = lane + 64*t;
    float px = xb[n*3+0], py = xb[n*3+1], pz = xb[n*3+2];
    float dot = lx*px + ly*py + lz*pz;
    float pn = px*px + py*py + pz*pz;
    float d2 = -2.0f*dot + ln + pn;
    unsigned u = __float_as_uint(d2);
    if (u == 0x80000000u) u = 0u;
    unsigned su = (u & 0x80000000u) ? ~u : (u | 0x80000000u);
    pk[t] = ((unsigned long long)su << 32) | (unsigned)n;
  }
  for (int it = 0; it < KNB; ++it){
    unsigned long long m = ~0ull;
    #pragma unroll
    for (int t = 0; t < CNT; ++t) m = (pk[t] < m) ? pk[t] : m;
    #pragma unroll
    for (int s = 1; s < 64; s <<= 1){
      unsigned long long o = __shfl_xor(m, s, 64);
      m = (o < m) ? o : m;
    }
    if (lane == 0) knn[(size_t)row*KNB + it] = (int)(unsigned)(m & 0xffffffffu);
    #pragma unroll
    for (int t = 0; t < CNT; ++t) if (pk[t] == m) pk[t] = ~0ull;
  }
}

__global__ __launch_bounds__(256) void k_diff_stats(const float* __restrict__ xyz,
                                                    const float* __restrict__ lc,
                                                    const int* __restrict__ knn,
                                                    int ncur, int g, double* __restrict__ out){
  long long gid = (long long)blockIdx.x*256 + threadIdx.x;
  long long total = (long long)NB*g*KNB;
  double s = 0.0, s2 = 0.0;
  if (gid < total){
    long long jj = gid / KNB;
    int nn = knn[gid];
    const float* p = xyz + ((size_t)(jj/g)*ncur + nn)*3;
    const float* c = lc + (size_t)jj*3;
    #pragma unroll
    for (int a = 0; a < 3; ++a){ float df = p[a] - c[a]; double d = (double)df; s += d; s2 += d*d; }
  }
  __shared__ double sa[256], sb[256];
  int t = threadIdx.x;
  sa[t] = s; sb[t] = s2; __syncthreads();
  for (int o = 128; o > 0; o >>= 1){
    if (t < o){ sa[t] += sa[t+o]; sb[t] += sb[t+o]; }
    __syncthreads();
  }
  if (t == 0){ atomicAdd(&out[0], sa[0]); atomicAdd(&out[1], sb[0]); }
}

__global__ void k_scalar_fin(const double* __restrict__ dst, double Mn, float* __restrict__ inv_std){
  double s = dst[0], s2 = dst[1];
  double mean = s / Mn;
  double var = (s2 - s*mean) / (Mn - 1.0);     // ddof=1
  if (var < 0.0) var = 0.0;
  float stdv = sqrtf((float)var);
  *inv_std = 1.0f / (stdv + 1e-5f);
}

// ---------------- build W (4-batch chunk, bf16) ----------------
__global__ __launch_bounds__(256) void k_build_w4(const float* __restrict__ feats,
                                                  const float* __restrict__ xyz,
                                                  const float* __restrict__ lc,
                                                  const int* __restrict__ fps,
                                                  const int* __restrict__ knn,
                                                  const float* __restrict__ inv_std,
                                                  uint16_t* __restrict__ W4,
                                                  int C, int g, int ncur, int f, int b0){
  long long idx = (long long)blockIdx.x*256 + threadIdx.x;
  int C2 = 6*f;
  long long total = 4LL*C2*g*KNB;
  if (idx >= total) return;
  int k  = (int)(idx % KNB);
  int j  = (int)((idx / KNB) % g);
  int ch = (int)((idx / ((long long)KNB*g)) % C2);
  int bl = (int)(idx / ((long long)KNB*g*C2));
  int b = b0 + bl;
  int nn = knn[((size_t)(b*g+j))*KNB + k];
  int axis = ch / (2*f);
  int r = ch % (2*f);
  int t = (r < f) ? r : r - f;
  float is = *inv_std;
  float fr = freq_of(t, f);
  float diff = xyz[((size_t)b*ncur + nn)*3 + axis] - lc[((size_t)(b*g+j))*3 + axis];
  float arg = 100.0f * (diff * is) * fr;
  float pe = (r < f) ? sinf(arg) : cosf(arg);
  float kx;
  if (ch < C) kx = feats[((size_t)b*C + ch)*ncur + nn];
  else { int ctr = fps[b*g+j]; kx = feats[((size_t)b*C + (ch - C))*ncur + ctr]; }
  W4[idx] = f2bf(kx + pe);
}

// ---------------- GEMM1: H = w1 * W (+b1), bf16 out, fused BN1 stats ----------------
__global__ __launch_bounds__(256) void k_gemm1(const float* __restrict__ A,       // [hid x C2] f32
                                               const uint16_t* __restrict__ W4,   // [4 x C2 x M] bf16
                                               const float* __restrict__ bias,
                                               uint16_t* __restrict__ Hout,       // [16 x hid x M] bf16
                                               float* __restrict__ SUMf, float* __restrict__ SQf,
                                               int Cout, int Cin, int M, int b0){
  __shared__ float As[8][64];
  __shared__ float Bs[8][64];
  int bl = blockIdx.z;
  int b = b0 + bl;
  int n0 = blockIdx.x * 64;
  int r0 = blockIdx.y * 64;
  int tid = threadIdx.x;
  int tx = tid & 15, ty = tid >> 4;
  float acc[4][4] = {{0.f}};
  const uint16_t* Bb = W4 + (size_t)bl * Cin * M;
  int lar = tid >> 2;
  int lak = (tid & 3) * 2;
  int lbk = tid >> 5;
  int lbc = (tid & 31) * 2;
  for (int k0 = 0; k0 < Cin; k0 += 8){
    float2 va = make_float2(0.f, 0.f);
    int row = r0 + lar;
    if (row < Cout) va = *(const float2*)(A + (size_t)row*Cin + k0 + lak);
    As[lak][lar] = va.x; As[lak+1][lar] = va.y;
    uint32_t vb = *(const uint32_t*)(Bb + (size_t)(k0 + lbk)*M + n0 + lbc);
    Bs[lbk][lbc]   = __uint_as_float(vb << 16);
    Bs[lbk][lbc+1] = __uint_as_float(vb & 0xffff0000u);
    __syncthreads();
    #pragma unroll
    for (int kk = 0; kk < 8; ++kk){
      float a0 = As[kk][ty*4+0], a1 = As[kk][ty*4+1], a2 = As[kk][ty*4+2], a3 = As[kk][ty*4+3];
      float b0v = Bs[kk][tx*4+0], b1v = Bs[kk][tx*4+1], b2v = Bs[kk][tx*4+2], b3v = Bs[kk][tx*4+3];
      acc[0][0] += a0*b0v; acc[0][1] += a0*b1v; acc[0][2] += a0*b2v; acc[0][3] += a0*b3v;
      acc[1][0] += a1*b0v; acc[1][1] += a1*b1v; acc[1][2] += a1*b2v; acc[1][3] += a1*b3v;
      acc[2][0] += a2*b0v; acc[2][1] += a2*b1v; acc[2][2] += a2*b2v; acc[2][3] += a2*b3v;
      acc[3][0] += a3*b0v; acc[3][1] += a3*b1v; acc[3][2] += a3*b2v; acc[3][3] += a3*b3v;
    }
    __syncthreads();
  }
  #pragma unroll
  for (int i = 0; i < 4; ++i){
    int row = r0 + ty*4 + i;
    float s = 0.f, s2 = 0.f;
    if (row < Cout){
      float bz = bias[row];
      float v0 = acc[i][0]+bz, v1 = acc[i][1]+bz, v2 = acc[i][2]+bz, v3 = acc[i][3]+bz;
      ushort4 st = make_ushort4(f2bf(v0), f2bf(v1), f2bf(v2), f2bf(v3));
      *(ushort4*)(Hout + ((size_t)b*Cout + row)*M + n0 + tx*4) = st;
      s  = v0+v1+v2+v3;
      s2 = v0*v0+v1*v1+v2*v2+v3*v3;
    }
    for (int o = 8; o > 0; o >>= 1){ s += __shfl_xor(s, o, 16); s2 += __shfl_xor(s2, o, 16); }
    if (tx == 0 && row < Cout){ atomicAdd(&SUMf[row], s); atomicAdd(&SQf[row], s2); }
  }
}

// ---------------- GEMM2: c2 = w2 * relu(bn1(H)) (+b2) ----------------
template<int FINAL>
__global__ __launch_bounds__(256) void k_gemm2(const float* __restrict__ A,       // [C2 x hid]
                                               const uint16_t* __restrict__ H,    // [16 x hid x M] bf16
                                               const float* __restrict__ sc1, const float* __restrict__ sh1,
                                               const float* __restrict__ bias2,
                                               float* __restrict__ SUMf, float* __restrict__ SQf,
                                               const float* __restrict__ sc2, const float* __restrict__ sh2,
                                               const float* __restrict__ feats,
                                               const float* __restrict__ xyz,
                                               const float* __restrict__ lc,
                                               const int* __restrict__ fps,
                                               const int* __restrict__ knn,
                                               const float* __restrict__ inv_std,
                                               float* __restrict__ fout,          // [16 x C2 x g]
                                               int Cout, int Cin, int M,
                                               int C, int g, int ncur, int f){
  __shared__ float As[8][64];
  __shared__ float Bs[8][64];
  int b = blockIdx.z;
  int n0 = blockIdx.x * 64;
  int r0 = blockIdx.y * 64;
  int tid = threadIdx.x;
  int tx = tid & 15, ty = tid >> 4;
  float acc[4][4] = {{0.f}};
  const uint16_t* Hb = H + (size_t)b * Cin * M;
  int lar = tid >> 2;
  int lak = (tid & 3) * 2;
  int lbk = tid >> 5;
  int lbc = (tid & 31) * 2;
  for (int k0 = 0; k0 < Cin; k0 += 8){
    float2 va = make_float2(0.f, 0.f);
    int row = r0 + lar;
    if (row < Cout) va = *(const float2*)(A + (size_t)row*Cin + k0 + lak);
    As[lak][lar] = va.x; As[lak+1][lar] = va.y;
    int krow = k0 + lbk;
    float a1 = sc1[krow], a0 = sh1[krow];
    uint32_t vb = *(const uint32_t*)(Hb + (size_t)krow*M + n0 + lbc);
    Bs[lbk][lbc]   = fmaxf(__uint_as_float(vb << 16)       * a1 + a0, 0.f);
    Bs[lbk][lbc+1] = fmaxf(__uint_as_float(vb & 0xffff0000u)* a1 + a0, 0.f);
    __syncthreads();
    #pragma unroll
    for (int kk = 0; kk < 8; ++kk){
      float a0v = As[kk][ty*4+0], a1v = As[kk][ty*4+1], a2v = As[kk][ty*4+2], a3v = As[kk][ty*4+3];
      float b0v = Bs[kk][tx*4+0], b1v = Bs[kk][tx*4+1], b2v = Bs[kk][tx*4+2], b3v = Bs[kk][tx*4+3];
      acc[0][0] += a0v*b0v; acc[0][1] += a0v*b1v; acc[0][2] += a0v*b2v; acc[0][3] += a0v*b3v;
      acc[1][0] += a1v*b0v; acc[1][1] += a1v*b1v; acc[1][2] += a1v*b2v; acc[1][3] += a1v*b3v;
      acc[2][0] += a2v*b0v; acc[2][1] += a2v*b1v; acc[2][2] += a2v*b2v; acc[2][3] += a2v*b3v;
      acc[3][0] += a3v*b0v; acc[3][1] += a3v*b1v; acc[3][2] += a3v*b2v; acc[3][3] += a3v*b3v;
    }
    __syncthreads();
  }
  if (FINAL == 0){
    #pragma unroll
    for (int i = 0; i < 4; ++i){
      int row = r0 + ty*4 + i;
      float s = 0.f, s2 = 0.f;
      if (row < Cout){
        float bz = bias2[row];
        float v0 = acc[i][0]+bz, v1 = acc[i][1]+bz, v2 = acc[i][2]+bz, v3 = acc[i][3]+bz;
        s  = v0+v1+v2+v3;
        s2 = v0*v0+v1*v1+v2*v2+v3*v3;
      }
      for (int o = 8; o > 0; o >>= 1){ s += __shfl_xor(s, o, 16); s2 += __shfl_xor(s2, o, 16); }
      if (tx == 0 && row < Cout){ atomicAdd(&SUMf[row], s); atomicAdd(&SQf[row], s2); }
    }
  } else {
    float is = *inv_std;
    #pragma unroll
    for (int i = 0; i < 4; ++i){
      int row = r0 + ty*4 + i;
      if (row >= Cout) continue;
      float bz = bias2[row];
      float m2 = sc2[row], a2s = sh2[row];
      int axis = row / (2*f);
      int r = row % (2*f);
      int t = (r < f) ? r : r - f;
      float fr = freq_of(t, f);
      bool isCtr = (row >= C);
      int chF = isCtr ? (row - C) : row;
      int curj = -1; float curmax = 0.f;
      #pragma unroll
      for (int jj = 0; jj < 4; ++jj){
        int n = n0 + tx*4 + jj;
        int jg = n / KNB;
        int kk = n - jg*KNB;
        int nn = knn[((size_t)(b*g+jg))*KNB + kk];
        float diff = xyz[((size_t)b*ncur + nn)*3 + axis] - lc[((size_t)(b*g+jg))*3 + axis];
        float arg = 100.0f * (diff * is) * fr;
        float pe = (r < f) ? sinf(arg) : cosf(arg);
        int src = isCtr ? fps[b*g+jg] : nn;
        float kx = feats[((size_t)b*C + chF)*ncur + src];
        float wv = kx + pe;
        float v = fmaxf(m2*(acc[i][jj]+bz) + a2s + wv, 0.f);
        if (jg != curj){
          if (curj >= 0)
            atomicMax((unsigned int*)&fout[((size_t)b*Cout + row)*g + curj], __float_as_uint(curmax));
          curj = jg; curmax = v;
        } else {
          curmax = fmaxf(curmax, v);
        }
      }
      atomicMax((unsigned int*)&fout[((size_t)b*Cout + row)*g + curj], __float_as_uint(curmax));
    }
  }
}

__global__ void k_copy(const float* __restrict__ src, float* __restrict__ dst, int n){
  int i = blockIdx.x*256 + threadIdx.x;
  if (i < n) dst[i] = src[i];
}

// ---------------- host driver ----------------
extern "C" void kernel_launch(void* const* d_in, const int* in_sizes, int n_in,
                              void* d_out, int out_size, void* d_ws, size_t ws_size,
                              hipStream_t stream){
  (void)in_sizes; (void)n_in; (void)out_size; (void)ws_size;
  const float* xyz0 = (const float*)d_in[0];
  const float* xin  = (const float*)d_in[1];
  const float* ew   = (const float*)d_in[2];
  const float* eg   = (const float*)d_in[3];
  const float* ebb  = (const float*)d_in[4];

  char* ws = (char*)d_ws;
  uint16_t* W4  = (uint16_t*)(ws + OFF_W4);
  uint16_t* Hb  = (uint16_t*)(ws + OFF_Hb);
  float* FA  = (float*)(ws + OFF_FA);
  float* FB  = (float*)(ws + OFF_FB);
  float* XA  = (float*)(ws + OFF_XA);
  float* XB  = (float*)(ws + OFF_XB);
  int*   FPS = (int*)(ws + OFF_FPS);
  int*   KNN = (int*)(ws + OFF_KNN);
  float* SUMf = (float*)(ws + OFF_SUM);
  float* SQf  = (float*)(ws + OFF_SQ);
  float* SC1 = (float*)(ws + OFF_SC1);
  float* SH1 = (float*)(ws + OFF_SH1);
  float* SC2 = (float*)(ws + OFF_SC2);
  float* SH2 = (float*)(ws + OFF_SH2);
  double* DST = (double*)(ws + OFF_DST);
  float* INV  = (float*)(ws + OFF_INV);
  float* out = (float*)d_out;

  // ---- embed: conv(3->72) + BN + ReLU -> FA ----
  k_embed<<<128, 256, 0, stream>>>(xin, ew, FA);
  hipMemsetAsync(SUMf, 0, 2*4608, stream);
  k_chan_stats_f32<<<dim3(72, NB), 256, 0, stream>>>(FA, 72, 2048, SUMf, SQf);
  k_bn_finalize_f32<<<1, 256, 0, stream>>>(SUMf, SQf, 72, 32768.0, eg, ebb, SC1, SH1);
  {
    long long tot = 16LL*72*2048;
    k_bn_apply<<<(int)((tot+255)/256), 256, 0, stream>>>(FA, SC1, SH1, 72, 2048, tot);
  }

  const int Cins[4] = {72,144,288,576};
  const int hids[4] = {72,144,32,576};
  const float* xcur = xyz0;
  float* fcur = FA;

  for (int i = 0; i < 4; ++i){
    int ncur = 2048 >> i, g = ncur >> 1;
    int C = Cins[i], C2 = 2*C, hid = hids[i], f = C2/6, M = g*KNB;
    float* lc = (i & 1) ? XB : XA;
    float* fout = (i < 3) ? ((i & 1) ? FA : FB) : (out + 6144);
    const float* w1  = (const float*)d_in[5+i*8+0];
    const float* b1  = (const float*)d_in[5+i*8+1];
    const float* g1  = (const float*)d_in[5+i*8+2];
    const float* bb1 = (const float*)d_in[5+i*8+3];
    const float* w2  = (const float*)d_in[5+i*8+4];
    const float* b2  = (const float*)d_in[5+i*8+5];
    const float* g2  = (const float*)d_in[5+i*8+6];
    const float* bb2 = (const float*)d_in[5+i*8+7];

    // foldlike split of key (0,1000+i): k2 = full cipher output of counter (0,1)
    uint32_t ka, kb;
    { uint32_t a = 0u, c = 1u; tf2x32(0u, (uint32_t)(1000+i), a, c);
      ka = a; kb = c; }

    int tot_fps = NB*g;
    k_fps<<<(tot_fps+255)/256, 256, 0, stream>>>(xcur, lc, FPS, ncur, g, ka, kb);

    if (ncur == 2048)      k_knn<32><<<NB*g, 64, 0, stream>>>(xcur, lc, KNN, ncur, g);
    else if (ncur == 1024) k_knn<16><<<NB*g, 64, 0, stream>>>(xcur, lc, KNN, ncur, g);
    else if (ncur == 512)  k_knn< 8><<<NB*g, 64, 0, stream>>>(xcur, lc, KNN, ncur, g);
    else                   k_knn< 4><<<NB*g, 64, 0, stream>>>(xcur, lc, KNN, ncur, g);

    hipMemsetAsync(DST, 0, 16, stream);
    int totk = NB*g*KNB;
    k_diff_stats<<<(totk+255)/256, 256, 0, stream>>>(xcur, lc, KNN, ncur, g, DST);
    k_scalar_fin<<<1, 1, 0, stream>>>(DST, (double)totk * 3.0, INV);

    // conv1 over 4-batch chunks with bf16 W, fused BN1 stats
    hipMemsetAsync(SUMf, 0, 2*4608, stream);
    long long totw4 = 4LL*C2*g*KNB;
    for (int c = 0; c < 4; ++c){
      k_build_w4<<<(int)((totw4+255)/256), 256, 0, stream>>>(fcur, xcur, lc, FPS, KNN, INV, W4, C, g, ncur, f, c*4);
      k_gemm1<<<dim3(M/64, (hid+63)/64, 4), 256, 0, stream>>>(w1, W4, b1, Hb, SUMf, SQf, hid, C2, M, c*4);
    }
    k_bn_finalize_f32<<<(hid+255)/256, 256, 0, stream>>>(SUMf, SQf, hid, (double)NB*M, g1, bb1, SC1, SH1);

    // conv2 pass 1: BN2 stats only
    hipMemsetAsync(SUMf, 0, 2*4608, stream);
    k_gemm2<0><<<dim3(M/64, (C2+63)/64, NB), 256, 0, stream>>>(w2, Hb, SC1, SH1, b2, SUMf, SQf,
        nullptr, nullptr, nullptr, nullptr, nullptr, nullptr, nullptr, nullptr, nullptr,
        C2, hid, M, C, g, ncur, f);
    k_bn_finalize_f32<<<(C2+255)/256, 256, 0, stream>>>(SUMf, SQf, C2, (double)NB*M, g2, bb2, SC2, SH2);

    // conv2 pass 2: fused bn2 + residual + relu + maxpool(K)
    hipMemsetAsync(fout, 0, 2359296ull*4, stream);
    k_gemm2<1><<<dim3(M/64, (C2+63)/64, NB), 256, 0, stream>>>(w2, Hb, SC1, SH1, b2, nullptr, nullptr,
        SC2, SH2, fcur, xcur, lc, FPS, KNN, INV, fout,
        C2, hid, M, C, g, ncur, f);

    xcur = lc; fcur = fout;
  }

  // final xyz = stage-3 lc (in XB)
  k_copy<<<(6144+255)/256, 256, 0, stream>>>(XB, out, 6144);
}